// Round 1
// baseline (92.512 us; speedup 1.0000x reference)
//
#include <hip/hip_runtime.h>

// TripletMarginLoss, N=512 anchors, D=128, labels in [0,64).
// loss = sum_{valid (i,j,k)} relu(dm[i,j]-dm[i,k]+1) / (count(> eps) + eps)
// valid(i,j,k) <=> j!=i && lab[j]==lab[i] && lab[k]!=lab[i]
//   (k!=i and k!=j are implied by lab[k]!=lab[i]==lab[j])

#define TN 512
#define TD 128
#define TMARGIN 1.0f
#define TEPS 1e-8f

__global__ __launch_bounds__(256) void triplet_loss_kernel(
    const float* __restrict__ emb,
    const int* __restrict__ labels,
    float* __restrict__ out,
    float* __restrict__ ws)   // ws[0]=sum, ws[1]=count, ws[2]=ticket (zeroed by memset)
{
    __shared__ float ei[TD];      // anchor embedding
    __shared__ float d[TN];       // dm row for this anchor
    __shared__ float pv[TN];      // positives: d[j] + margin
    __shared__ int   npos;
    __shared__ float red_s[4], red_c[4];

    const int i = blockIdx.x;
    const int t = threadIdx.x;
    const int lab_i = labels[i];

    if (t < TD) ei[t] = emb[i * TD + t];
    if (t == 0) npos = 0;
    __syncthreads();

    // dm row: each thread computes 2 dot products of length 128 (float4 loads)
    for (int j = t; j < TN; j += 256) {
        const float4* row = (const float4*)(emb + j * TD);
        float acc = 0.f;
#pragma unroll
        for (int c = 0; c < TD / 4; ++c) {
            float4 v = row[c];
            acc += v.x * ei[4 * c + 0] + v.y * ei[4 * c + 1]
                 + v.z * ei[4 * c + 2] + v.w * ei[4 * c + 3];
        }
        d[j] = acc;
    }
    __syncthreads();

    // collect positives for this anchor
    for (int j = t; j < TN; j += 256) {
        if (j != i && labels[j] == lab_i) {
            int idx = atomicAdd(&npos, 1);
            pv[idx] = d[j] + TMARGIN;
        }
    }
    __syncthreads();

    const int np = npos;
    float lsum = 0.f, lcnt = 0.f;
    // threads sweep negatives; inner loop over the few positives
    for (int k = t; k < TN; k += 256) {
        if (labels[k] != lab_i) {
            const float dn = d[k];
            for (int p = 0; p < np; ++p) {
                const float v = pv[p] - dn;
                if (v > 0.f)   lsum += v;
                if (v > TEPS)  lcnt += 1.f;
            }
        }
    }

    // wave(64) shuffle reduction, then cross-wave via LDS
#pragma unroll
    for (int off = 32; off > 0; off >>= 1) {
        lsum += __shfl_down(lsum, off);
        lcnt += __shfl_down(lcnt, off);
    }
    const int wave = t >> 6;
    if ((t & 63) == 0) { red_s[wave] = lsum; red_c[wave] = lcnt; }
    __syncthreads();

    if (t == 0) {
        const float bs = red_s[0] + red_s[1] + red_s[2] + red_s[3];
        const float bc = red_c[0] + red_c[1] + red_c[2] + red_c[3];
        atomicAdd(&ws[0], bs);   // device-scope by default on gfx950
        atomicAdd(&ws[1], bc);
        __threadfence();
        const unsigned tk = atomicAdd((unsigned*)&ws[2], 1u);
        if (tk == gridDim.x - 1) {
            // last block: read accumulators coherently (atomic RMW forces
            // device-scope access across XCD L2s) and finalize
            const float s = atomicAdd(&ws[0], 0.f);
            const float c = atomicAdd(&ws[1], 0.f);
            out[0] = s / (c + TEPS);
        }
    }
}

extern "C" void kernel_launch(void* const* d_in, const int* in_sizes, int n_in,
                              void* d_out, int out_size, void* d_ws, size_t ws_size,
                              hipStream_t stream) {
    const float* emb   = (const float*)d_in[0];
    const int* labels  = (const int*)d_in[1];   // harness delivers integer inputs as int32
    float* out = (float*)d_out;
    float* ws  = (float*)d_ws;

    // zero sum/count/ticket (harness poisons ws to 0xAA before every launch)
    hipMemsetAsync(ws, 0, 16, stream);
    triplet_loss_kernel<<<TN, 256, 0, stream>>>(emb, labels, out, ws);
}

// Round 2
// 63.224 us; speedup vs baseline: 1.4632x; 1.4632x over previous
//
#include <hip/hip_runtime.h>

// TripletMarginLoss, N=512 anchors, D=128, labels in [0,64).
// loss = sum_{valid (i,j,k)} relu(dm[i,j]-dm[i,k]+1) / (count(> eps) + eps)
// valid(i,j,k) <=> j!=i && lab[j]==lab[i] && lab[k]!=lab[i]
//   (k!=i and k!=j are implied by lab[k]!=lab[i]==lab[j])

#define TN 512
#define TD 128
#define TMARGIN 1.0f
#define TEPS 1e-8f

// Kernel 1: one block per anchor. Computes dm row (coalesced, 4 lanes/row),
// builds positive list, sweeps negatives, writes per-block {sum,count} to ws.
__global__ __launch_bounds__(256) void triplet_partial_kernel(
    const float* __restrict__ emb,
    const int* __restrict__ labels,
    float* __restrict__ ws)      // ws[2*i]=sum_i, ws[2*i+1]=count_i (plain stores)
{
    __shared__ float ei[TD];      // anchor embedding
    __shared__ float d[TN];       // dm row for this anchor
    __shared__ float pv[TN];      // positives: d[j] + margin
    __shared__ int   lab[TN];     // labels staged in LDS
    __shared__ int   npos;
    __shared__ float red_s[4], red_c[4];

    const int i = blockIdx.x;
    const int t = threadIdx.x;

    if (t < TD) ei[t] = emb[i * TD + t];
    for (int j = t; j < TN; j += 256) lab[j] = labels[j];
    if (t == 0) npos = 0;
    __syncthreads();

    const int lab_i = lab[i];

    // dm row, coalesced: 4 lanes per row. Quad q = t>>2 handles row p*64+q;
    // lane sub = t&3 reads float4 chunks sub, sub+4, ..., sub+28 (64B
    // contiguous per quad per load). Quad-reduce via 2-step shfl_xor.
    const int q   = t >> 2;
    const int sub = t & 3;
    const float4* ei4 = (const float4*)ei;
#pragma unroll
    for (int p = 0; p < 8; ++p) {
        const int row = p * 64 + q;
        const float4* rp = (const float4*)(emb + row * TD);
        float acc = 0.f;
#pragma unroll
        for (int m = 0; m < 8; ++m) {
            const int c = sub + 4 * m;
            float4 v = rp[c];
            float4 w = ei4[c];          // broadcast across quads (free)
            acc += v.x * w.x + v.y * w.y + v.z * w.z + v.w * w.w;
        }
        acc += __shfl_xor(acc, 1);
        acc += __shfl_xor(acc, 2);
        if (sub == 0) d[row] = acc;
    }
    __syncthreads();

    // collect positives for this anchor
    for (int j = t; j < TN; j += 256) {
        if (j != i && lab[j] == lab_i) {
            int idx = atomicAdd(&npos, 1);
            pv[idx] = d[j] + TMARGIN;
        }
    }
    __syncthreads();

    const int np = npos;
    float lsum = 0.f, lcnt = 0.f;
    // threads sweep negatives; inner loop over the few positives
    for (int k = t; k < TN; k += 256) {
        if (lab[k] != lab_i) {
            const float dn = d[k];
            for (int p = 0; p < np; ++p) {
                const float v = pv[p] - dn;
                if (v > 0.f)   lsum += v;
                if (v > TEPS)  lcnt += 1.f;
            }
        }
    }

    // wave(64) shuffle reduction, then cross-wave via LDS
#pragma unroll
    for (int off = 32; off > 0; off >>= 1) {
        lsum += __shfl_down(lsum, off);
        lcnt += __shfl_down(lcnt, off);
    }
    const int wave = t >> 6;
    if ((t & 63) == 0) { red_s[wave] = lsum; red_c[wave] = lcnt; }
    __syncthreads();

    if (t == 0) {
        ws[2 * i]     = red_s[0] + red_s[1] + red_s[2] + red_s[3];
        ws[2 * i + 1] = red_c[0] + red_c[1] + red_c[2] + red_c[3];
    }
}

// Kernel 2: one block reduces 512 {sum,count} pairs and finalizes.
__global__ __launch_bounds__(256) void triplet_reduce_kernel(
    const float* __restrict__ ws,
    float* __restrict__ out)
{
    __shared__ float red_s[4], red_c[4];
    const int t = threadIdx.x;
    float lsum = 0.f, lcnt = 0.f;
#pragma unroll
    for (int r = 0; r < 2; ++r) {
        const int j = t + 256 * r;
        lsum += ws[2 * j];
        lcnt += ws[2 * j + 1];
    }
#pragma unroll
    for (int off = 32; off > 0; off >>= 1) {
        lsum += __shfl_down(lsum, off);
        lcnt += __shfl_down(lcnt, off);
    }
    const int wave = t >> 6;
    if ((t & 63) == 0) { red_s[wave] = lsum; red_c[wave] = lcnt; }
    __syncthreads();
    if (t == 0) {
        const float s = red_s[0] + red_s[1] + red_s[2] + red_s[3];
        const float c = red_c[0] + red_c[1] + red_c[2] + red_c[3];
        out[0] = s / (c + TEPS);
    }
}

extern "C" void kernel_launch(void* const* d_in, const int* in_sizes, int n_in,
                              void* d_out, int out_size, void* d_ws, size_t ws_size,
                              hipStream_t stream) {
    const float* emb  = (const float*)d_in[0];
    const int* labels = (const int*)d_in[1];   // harness delivers integer inputs as int32
    float* out = (float*)d_out;
    float* ws  = (float*)d_ws;

    triplet_partial_kernel<<<TN, 256, 0, stream>>>(emb, labels, ws);
    triplet_reduce_kernel<<<1, 256, 0, stream>>>(ws, out);
}